// Round 1
// baseline (418.782 us; speedup 1.0000x reference)
//
#include <hip/hip_runtime.h>
#include <math.h>

#define V_PTS 8192
#define NQ    1024
#define TWO_PI 6.283185307179586f
#define INV_SQRT2 0.70710678118654752f

__device__ __forceinline__ float gelu_erf(float a) {
  return 0.5f * a * (1.0f + erff(a * INV_SQRT2));
}

// ---------------- Kernel A: xl = x @ W_lin + b_lin ----------------
__global__ __launch_bounds__(256) void xl_kernel(const float* __restrict__ x,
                                                 const float* __restrict__ Wl,
                                                 const float* __restrict__ bl,
                                                 float* __restrict__ xl) {
  __shared__ float sW[1024];
  __shared__ float sb[32];
  __shared__ float sx[256];
  const int t = threadIdx.x;
  for (int i = t; i < 1024; i += 256) sW[i] = Wl[i];
  if (t < 32) sb[t] = bl[t];
  const size_t base = (size_t)blockIdx.x * 256;   // 8 rows of 32
  sx[t] = x[base + t];
  __syncthreads();
  const int r = t >> 5, co = t & 31;
  float acc = sb[co];
#pragma unroll
  for (int ci = 0; ci < 32; ++ci) acc = fmaf(sx[r * 32 + ci], sW[ci * 32 + co], acc);
  xl[base + t] = acc;
}

// ---------------- Kernel B: one block per query ----------------
__global__ __launch_bounds__(256) void calm_kernel(
    const float* __restrict__ pos, const float* __restrict__ qpos,
    const float* __restrict__ qmw, const float* __restrict__ qmo,
    const float* __restrict__ Brff, const float* __restrict__ W1,
    const float* __restrict__ b1, const float* __restrict__ W2,
    const float* __restrict__ filt, const float* __restrict__ bout,
    const float* __restrict__ Wm1, const float* __restrict__ bm1,
    const float* __restrict__ Wm2, const float* __restrict__ bm2,
    const float* __restrict__ xl, float* __restrict__ out) {
  // s_big phases: [start..P5] W1 (1024 floats); [P6] Xsel chunk 16x512; [P7] G half 16x512
  __shared__ __align__(16) float s_big[16 * 512];   // 32 KB
  __shared__ __align__(16) float s_H2[128 * 36];    // 18 KB: [k][j<32]=kd*h, [32]=kd
  __shared__ int   s_seli[128];
  __shared__ float s_sele[128];
  __shared__ float s_kd[128];
  __shared__ __align__(16) float s_F[512];
  __shared__ float s_small[128];                    // brf 0..31 | b1 32..63 | qm 64..95 | qo 96..127
  __shared__ int   s_scan[256];
  __shared__ float s_red[256];
  __shared__ int   s_redi[4];
  __shared__ unsigned s_redu[4];
  __shared__ float s_y[256];
  __shared__ float s_z[1024];

  const int tid  = threadIdx.x;
  const int q    = blockIdx.x;
  const int lane = tid & 63;
  const int wv   = tid >> 6;

  // stage constants
  for (int i = tid; i < 1024; i += 256) s_big[i] = W1[i];
  if (tid < 32) {
    s_small[tid]      = Brff[tid];
    s_small[32 + tid] = b1[tid];
    s_small[64 + tid] = qmw[q * 32 + tid];
    s_small[96 + tid] = qmo[q * 32 + tid];
  }

  const float qx = qpos[2 * q], qy = qpos[2 * q + 1];

  // ---- Phase 1: squared torus distances, kept in 32 regs as uint (e>=0 -> monotone bits)
  unsigned u[32];
  unsigned umin = 0xFFFFFFFFu;
#pragma unroll
  for (int i = 0; i < 32; ++i) {
    const int v = i * 256 + tid;
    const float2 p = *(const float2*)(pos + 2 * v);
    float dx = qx - p.x + 0.5f; dx -= floorf(dx); dx -= 0.5f;
    float dy = qy - p.y + 0.5f; dy -= floorf(dy); dy -= 0.5f;
    const float e = dx * dx + dy * dy;
    u[i] = __float_as_uint(e);
    umin = min(umin, u[i]);
  }
  // block-min
#pragma unroll
  for (int off = 32; off > 0; off >>= 1) {
    unsigned o = (unsigned)__shfl_down((int)umin, off);
    umin = min(umin, o);
  }
  if (lane == 0) s_redu[wv] = umin;
  __syncthreads();
  const unsigned uminAll = min(min(s_redu[0], s_redu[1]), min(s_redu[2], s_redu[3]));
  __syncthreads();

  // ---- Phase 2: binary search for 128th-smallest value T (on uint bits)
  unsigned lo = 0u, hi = 0x3F000001u;   // e <= 0.5
  while (lo < hi) {
    const unsigned mid = (lo + hi) >> 1;
    int c = 0;
#pragma unroll
    for (int i = 0; i < 32; ++i) c += (u[i] <= mid) ? 1 : 0;
#pragma unroll
    for (int off = 32; off > 0; off >>= 1) c += __shfl_down(c, off);
    if (lane == 0) s_redi[wv] = c;
    __syncthreads();
    const int tot = s_redi[0] + s_redi[1] + s_redi[2] + s_redi[3];
    __syncthreads();
    if (tot >= 128) hi = mid; else lo = mid + 1;
  }
  const unsigned T = lo;

  // ---- Phase 3: deterministic compaction (prefix scan, no atomics)
  int clt = 0, ceq = 0;
#pragma unroll
  for (int i = 0; i < 32; ++i) { clt += (u[i] < T) ? 1 : 0; ceq += (u[i] == T) ? 1 : 0; }
  const int packed = clt | (ceq << 16);
  s_scan[tid] = packed;
  __syncthreads();
  for (int off = 1; off < 256; off <<= 1) {
    const int v2 = (tid >= off) ? s_scan[tid - off] : 0;
    __syncthreads();
    s_scan[tid] += v2;
    __syncthreads();
  }
  const int incl  = s_scan[tid];
  const int totLt = s_scan[255] & 0xFFFF;
  int plt = (incl & 0xFFFF) - clt;
  int peq = totLt + ((incl >> 16) - ceq);
#pragma unroll
  for (int i = 0; i < 32; ++i) {
    const int v = i * 256 + tid;
    if (u[i] < T)        { s_seli[plt] = v; s_sele[plt] = __uint_as_float(u[i]); ++plt; }
    else if (u[i] == T)  { if (peq < 128) { s_seli[peq] = v; s_sele[peq] = __uint_as_float(u[i]); } ++peq; }
  }
  __syncthreads();

  // ---- Phase 4: k_dist softmax
  const float eminf = __uint_as_float(uminAll);
  const float emaxf = __uint_as_float(T);
  if (tid < 128) {
    const float nrm = (s_sele[tid] - eminf) / ((emaxf - eminf) + 1e-8f);
    const float w = expf(-nrm);
    s_kd[tid]  = w;
    s_red[tid] = w;
  }
  __syncthreads();
  for (int off = 64; off > 0; off >>= 1) {
    if (tid < off) s_red[tid] += s_red[tid + off];
    __syncthreads();
  }
  const float wsum = s_red[0];
  if (tid < 128) s_kd[tid] /= wsum;
  __syncthreads();

  // ---- Phase 5: RFF -> modulated MLP -> H2[k][j] = kd*h ; H2[k][32] = kd
  {
    const int k = tid >> 1, hh = tid & 1;
    const int v = s_seli[k];
    const float2 p = *(const float2*)(pos + 2 * v);
    float dx = qx - p.x + 0.5f; dx -= floorf(dx); dx -= 0.5f;
    float dy = qy - p.y + 0.5f; dy -= floorf(dy); dy -= 0.5f;
    float sn[16], cs[16];
#pragma unroll
    for (int i = 0; i < 16; ++i) {
      const float pr = TWO_PI * (dx * s_small[i] + dy * s_small[16 + i]);
      sn[i] = sinf(pr); cs[i] = cosf(pr);
    }
    const float kdv = s_kd[k];
#pragma unroll
    for (int jj = 0; jj < 16; ++jj) {
      const int j = hh * 16 + jj;
      float s = s_small[32 + j];
#pragma unroll
      for (int r = 0; r < 16; ++r) s = fmaf(sn[r], s_big[r * 32 + j], s);
#pragma unroll
      for (int r = 0; r < 16; ++r) s = fmaf(cs[r], s_big[(16 + r) * 32 + j], s);
      const float a = s * s_small[64 + j] + s_small[96 + j];
      s_H2[k * 36 + j] = kdv * gelu_erf(a);
    }
    if (hh == 0) s_H2[k * 36 + 32] = kdv;
  }
  __syncthreads();

  // ---- Phase 6: G[33 x 512] = H2^T @ Xsel, register-blocked (8j x 8p / thread)
  float acc[8][8];
#pragma unroll
  for (int a = 0; a < 8; ++a)
#pragma unroll
    for (int b = 0; b < 8; ++b) acc[a][b] = 0.0f;
  float facc[8] = {0, 0, 0, 0, 0, 0, 0, 0};

  for (int ch = 0; ch < 8; ++ch) {
    __syncthreads();   // previous consumers of s_big done
#pragma unroll
    for (int i = 0; i < 8; ++i) {
      const int f   = i * 256 + tid;           // 0..2047 float4 slots
      const int kk  = f >> 7;                  // 0..15
      const int off = (f & 127) << 2;          // word offset 0..508
      const int v   = s_seli[ch * 16 + kk];
      const int bt  = off >> 5, c = off & 31;
      const float4 val = *(const float4*)(xl + ((size_t)bt * V_PTS + v) * 32 + c);
      *(float4*)(s_big + kk * 512 + off) = val;
    }
    __syncthreads();
#pragma unroll
    for (int kk = 0; kk < 16; ++kk) {
      const float* hrow = s_H2 + (ch * 16 + kk) * 36;
      const float4 alo = *(const float4*)(hrow + wv * 8);
      const float4 ahi = *(const float4*)(hrow + wv * 8 + 4);
      const float4 b0  = *(const float4*)(s_big + kk * 512 + lane * 4);
      const float4 b1v = *(const float4*)(s_big + kk * 512 + 256 + lane * 4);
      const float av[8] = {alo.x, alo.y, alo.z, alo.w, ahi.x, ahi.y, ahi.z, ahi.w};
      const float bv[8] = {b0.x, b0.y, b0.z, b0.w, b1v.x, b1v.y, b1v.z, b1v.w};
#pragma unroll
      for (int jj = 0; jj < 8; ++jj)
#pragma unroll
        for (int pp = 0; pp < 8; ++pp)
          acc[jj][pp] = fmaf(av[jj], bv[pp], acc[jj][pp]);
      if (wv == 0) {
        const float kdv = hrow[32];
#pragma unroll
        for (int pp = 0; pp < 8; ++pp) facc[pp] = fmaf(kdv, bv[pp], facc[pp]);
      }
    }
  }

  // ---- Phase 7: y = G*W2 + F*filt (two j-halves through s_big), then epilogue MLP
  const int obt = tid >> 4, od = tid & 15;
  float accy = 0.0f;
  for (int pass = 0; pass < 2; ++pass) {
    __syncthreads();
    if ((wv >> 1) == pass) {
      const int wl = wv & 1;
#pragma unroll
      for (int jj = 0; jj < 8; ++jj) {
        const int j2 = wl * 8 + jj;
        *(float4*)(s_big + j2 * 512 + lane * 4)       = make_float4(acc[jj][0], acc[jj][1], acc[jj][2], acc[jj][3]);
        *(float4*)(s_big + j2 * 512 + 256 + lane * 4) = make_float4(acc[jj][4], acc[jj][5], acc[jj][6], acc[jj][7]);
      }
    }
    if (pass == 0 && wv == 0) {
      *(float4*)(s_F + lane * 4)       = make_float4(facc[0], facc[1], facc[2], facc[3]);
      *(float4*)(s_F + 256 + lane * 4) = make_float4(facc[4], facc[5], facc[6], facc[7]);
    }
    __syncthreads();
    for (int j2 = 0; j2 < 16; ++j2) {
      const float* grow = s_big + j2 * 512 + obt * 32;
      const float* w2p  = W2 + (size_t)(pass * 16 + j2) * 512 + od;
#pragma unroll
      for (int c = 0; c < 32; ++c)
        accy = fmaf(grow[c], w2p[c * 16], accy);
    }
  }
#pragma unroll
  for (int c = 0; c < 32; ++c)
    accy = fmaf(s_F[obt * 32 + c], filt[c * 16 + od], accy);
  accy += bout[od];
  const float ya = gelu_erf(accy);
  s_y[tid] = ya;
  __syncthreads();
#pragma unroll
  for (int hh = 0; hh < 4; ++hh) {
    const int h = od * 4 + hh;
    float s = bm1[h];
#pragma unroll
    for (int d2 = 0; d2 < 16; ++d2) s = fmaf(s_y[obt * 16 + d2], Wm1[d2 * 64 + h], s);
    s_z[obt * 64 + h] = gelu_erf(s);
  }
  __syncthreads();
  float o = bm2[od];
#pragma unroll
  for (int h = 0; h < 64; ++h) o = fmaf(s_z[obt * 64 + h], Wm2[h * 16 + od], o);
  o += ya;
  out[((size_t)obt * NQ + q) * 16 + od] = o;

  // second output: query_pos passthrough
  if (tid < 2) out[16 * NQ * 16 + q * 2 + tid] = qpos[q * 2 + tid];
}

extern "C" void kernel_launch(void* const* d_in, const int* in_sizes, int n_in,
                              void* d_out, int out_size, void* d_ws, size_t ws_size,
                              hipStream_t stream) {
  const float* x    = (const float*)d_in[0];
  const float* pos  = (const float*)d_in[1];
  const float* qpos = (const float*)d_in[2];
  const float* qmw  = (const float*)d_in[3];
  const float* qmo  = (const float*)d_in[4];
  const float* Wl   = (const float*)d_in[5];
  const float* bl   = (const float*)d_in[6];
  const float* Brff = (const float*)d_in[7];
  const float* W1   = (const float*)d_in[8];
  const float* b1   = (const float*)d_in[9];
  const float* W2   = (const float*)d_in[10];
  const float* filt = (const float*)d_in[11];
  const float* bo   = (const float*)d_in[12];
  const float* Wm1  = (const float*)d_in[13];
  const float* bm1  = (const float*)d_in[14];
  const float* Wm2  = (const float*)d_in[15];
  const float* bm2  = (const float*)d_in[16];
  float* out = (float*)d_out;
  float* xl  = (float*)d_ws;   // 16*8192*32 floats = 16 MB

  hipLaunchKernelGGL(xl_kernel, dim3(16384), dim3(256), 0, stream, x, Wl, bl, xl);
  hipLaunchKernelGGL(calm_kernel, dim3(NQ), dim3(256), 0, stream,
                     pos, qpos, qmw, qmo, Brff, W1, b1, W2, filt, bo,
                     Wm1, bm1, Wm2, bm2, xl, out);
}

// Round 2
// 237.716 us; speedup vs baseline: 1.7617x; 1.7617x over previous
//
#include <hip/hip_runtime.h>
#include <math.h>

#define V_PTS 8192
#define NQ    1024
#define TWO_PI 6.283185307179586f
#define INV_SQRT2 0.70710678118654752f

__device__ __forceinline__ float gelu_erf(float a) {
  return 0.5f * a * (1.0f + erff(a * INV_SQRT2));
}

// ---------------- Kernel P: W2p[j][c'][d] = sum_c Wl[c'][c]*W2e[j][c][d] ----------------
// W2e rows: j<32 -> W2 row j; j==32 -> filt.  Also W2b[j][d] = sum_c bl[c]*W2e[j][c][d].
__global__ __launch_bounds__(256) void prep_kernel(const float* __restrict__ Wl,
                                                   const float* __restrict__ bl,
                                                   const float* __restrict__ W2,
                                                   const float* __restrict__ filt,
                                                   float* __restrict__ W2p,
                                                   float* __restrict__ W2b) {
  __shared__ float sWl[1024];
  const int tid = threadIdx.x;
  for (int i = tid; i < 1024; i += 256) sWl[i] = Wl[i];
  __syncthreads();
  const int base = blockIdx.x * 528;   // 32 blocks * 528 = 16896 = 33*512
  for (int i = 0; i < 528; i += 256) {
    const int li = i + tid;
    if (li < 528) {
      const int idx = base + li;
      if (idx < 16896) {
        const int j = idx >> 9, r = idx & 511, cp = r >> 4, d = r & 15;
        const float* src = (j < 32) ? (W2 + (j << 9)) : filt;
        float acc = 0.0f;
#pragma unroll
        for (int c = 0; c < 32; ++c) acc = fmaf(sWl[cp * 32 + c], src[(c << 4) + d], acc);
        W2p[idx] = acc;
      }
    }
  }
  if (blockIdx.x == 0) {
    for (int idx = tid; idx < 528; idx += 256) {
      const int j = idx >> 4, d = idx & 15;
      const float* src = (j < 32) ? (W2 + (j << 9)) : filt;
      float acc = 0.0f;
#pragma unroll
      for (int c = 0; c < 32; ++c) acc = fmaf(bl[c], src[(c << 4) + d], acc);
      W2b[idx] = acc;
    }
  }
}

// ---------------- Kernel B: per-query selection + H2 generation ----------------
__global__ __launch_bounds__(256) void sel_kernel(
    const float* __restrict__ pos, const float* __restrict__ qpos,
    const float* __restrict__ qmw, const float* __restrict__ qmo,
    const float* __restrict__ Brff, const float* __restrict__ W1,
    const float* __restrict__ b1, const float* __restrict__ bout,
    const float* __restrict__ W2b,
    int* __restrict__ seli_ws, float* __restrict__ H2t_ws,
    float* __restrict__ ybias_ws, float* __restrict__ out) {
  __shared__ float s_W1[1024];
  __shared__ float s_H2f[128 * 36];    // [k][j<32]=kd*h, [32]=kd, [33..36)=0
  __shared__ int   s_seli[128];
  __shared__ float s_sele[128];
  __shared__ float s_kd[128];
  __shared__ float s_small[128];       // brf 0..31 | b1 32..63 | qm 64..95 | qo 96..127
  __shared__ int   s_scan[256];
  __shared__ float s_red[256];
  __shared__ int   s_redi[4];
  __shared__ unsigned s_redu[4];
  __shared__ float s_hsum[36];

  const int tid  = threadIdx.x;
  const int q    = blockIdx.x;
  const int lane = tid & 63;
  const int wv   = tid >> 6;

  for (int i = tid; i < 1024; i += 256) s_W1[i] = W1[i];
  if (tid < 32) {
    s_small[tid]      = Brff[tid];
    s_small[32 + tid] = b1[tid];
    s_small[64 + tid] = qmw[q * 32 + tid];
    s_small[96 + tid] = qmo[q * 32 + tid];
  }

  const float qx = qpos[2 * q], qy = qpos[2 * q + 1];

  // ---- Phase 1: squared torus distances as monotone uint bits
  unsigned u[32];
  unsigned umin = 0xFFFFFFFFu;
#pragma unroll
  for (int i = 0; i < 32; ++i) {
    const int v = i * 256 + tid;
    const float2 p = *(const float2*)(pos + 2 * v);
    float dx = qx - p.x + 0.5f; dx -= floorf(dx); dx -= 0.5f;
    float dy = qy - p.y + 0.5f; dy -= floorf(dy); dy -= 0.5f;
    const float e = dx * dx + dy * dy;
    u[i] = __float_as_uint(e);
    umin = min(umin, u[i]);
  }
#pragma unroll
  for (int off = 32; off > 0; off >>= 1) {
    unsigned o = (unsigned)__shfl_down((int)umin, off);
    umin = min(umin, o);
  }
  if (lane == 0) s_redu[wv] = umin;
  __syncthreads();
  const unsigned uminAll = min(min(s_redu[0], s_redu[1]), min(s_redu[2], s_redu[3]));
  __syncthreads();

  // ---- Phase 2: binary search for 128th-smallest (uint bits)
  unsigned lo = 0u, hi = 0x3F000001u;
  while (lo < hi) {
    const unsigned mid = (lo + hi) >> 1;
    int c = 0;
#pragma unroll
    for (int i = 0; i < 32; ++i) c += (u[i] <= mid) ? 1 : 0;
#pragma unroll
    for (int off = 32; off > 0; off >>= 1) c += __shfl_down(c, off);
    if (lane == 0) s_redi[wv] = c;
    __syncthreads();
    const int tot = s_redi[0] + s_redi[1] + s_redi[2] + s_redi[3];
    __syncthreads();
    if (tot >= 128) hi = mid; else lo = mid + 1;
  }
  const unsigned T = lo;

  // ---- Phase 3: deterministic compaction
  int clt = 0, ceq = 0;
#pragma unroll
  for (int i = 0; i < 32; ++i) { clt += (u[i] < T) ? 1 : 0; ceq += (u[i] == T) ? 1 : 0; }
  s_scan[tid] = clt | (ceq << 16);
  __syncthreads();
  for (int off = 1; off < 256; off <<= 1) {
    const int v2 = (tid >= off) ? s_scan[tid - off] : 0;
    __syncthreads();
    s_scan[tid] += v2;
    __syncthreads();
  }
  const int incl  = s_scan[tid];
  const int totLt = s_scan[255] & 0xFFFF;
  int plt = (incl & 0xFFFF) - clt;
  int peq = totLt + ((incl >> 16) - ceq);
#pragma unroll
  for (int i = 0; i < 32; ++i) {
    const int v = i * 256 + tid;
    if (u[i] < T)        { s_seli[plt] = v; s_sele[plt] = __uint_as_float(u[i]); ++plt; }
    else if (u[i] == T)  { if (peq < 128) { s_seli[peq] = v; s_sele[peq] = __uint_as_float(u[i]); } ++peq; }
  }
  __syncthreads();

  // ---- Phase 4: k_dist softmax
  const float eminf = __uint_as_float(uminAll);
  const float emaxf = __uint_as_float(T);
  if (tid < 128) {
    const float nrm = (s_sele[tid] - eminf) / ((emaxf - eminf) + 1e-8f);
    const float w = expf(-nrm);
    s_kd[tid]  = w;
    s_red[tid] = w;
  }
  __syncthreads();
  for (int off = 64; off > 0; off >>= 1) {
    if (tid < off) s_red[tid] += s_red[tid + off];
    __syncthreads();
  }
  const float wsum = s_red[0];
  if (tid < 128) s_kd[tid] /= wsum;
  __syncthreads();

  // ---- Phase 5: RFF -> modulated MLP -> H2f[k][j]=kd*h, [32]=kd, [33..36)=0
  {
    const int k = tid >> 1, hh = tid & 1;
    const int v = s_seli[k];
    const float2 p = *(const float2*)(pos + 2 * v);
    float dx = qx - p.x + 0.5f; dx -= floorf(dx); dx -= 0.5f;
    float dy = qy - p.y + 0.5f; dy -= floorf(dy); dy -= 0.5f;
    float sn[16], cs[16];
#pragma unroll
    for (int i = 0; i < 16; ++i) {
      const float pr = TWO_PI * (dx * s_small[i] + dy * s_small[16 + i]);
      sn[i] = sinf(pr); cs[i] = cosf(pr);
    }
    const float kdv = s_kd[k];
#pragma unroll
    for (int jj = 0; jj < 16; ++jj) {
      const int j = hh * 16 + jj;
      float s = s_small[32 + j];
#pragma unroll
      for (int r = 0; r < 16; ++r) s = fmaf(sn[r], s_W1[r * 32 + j], s);
#pragma unroll
      for (int r = 0; r < 16; ++r) s = fmaf(cs[r], s_W1[(16 + r) * 32 + j], s);
      const float a = s * s_small[64 + j] + s_small[96 + j];
      s_H2f[k * 36 + j] = kdv * gelu_erf(a);
    }
    if (hh == 0) s_H2f[k * 36 + 32] = kdv;
    else { s_H2f[k * 36 + 33] = 0.0f; s_H2f[k * 36 + 34] = 0.0f; s_H2f[k * 36 + 35] = 0.0f; }
  }
  __syncthreads();

  // ---- outputs
  if (tid < 128) seli_ws[q * 128 + tid] = s_seli[tid];
  for (int idx = tid; idx < 4608; idx += 256) {          // H2t [36][128]
    const int j = idx >> 7, k = idx & 127;
    H2t_ws[q * 4608 + idx] = s_H2f[k * 36 + j];
  }
  if (tid < 36) {
    float s = 0.0f;
    for (int k = 0; k < 128; ++k) s += s_H2f[k * 36 + tid];
    s_hsum[tid] = s;
  }
  __syncthreads();
  if (tid < 16) {
    float b = bout[tid];
#pragma unroll
    for (int j = 0; j < 33; ++j) b = fmaf(s_hsum[j], W2b[j * 16 + tid], b);
    ybias_ws[q * 16 + tid] = b;
  }
  if (tid < 2) out[16 * NQ * 16 + q * 2 + tid] = qpos[q * 2 + tid];
}

// ---------------- Kernel C: gather-GEMM + epilogue, block = (q, bt-group of 8) ----------------
__global__ __launch_bounds__(256) void main_kernel(
    const float* __restrict__ x, const int* __restrict__ seli_ws,
    const float* __restrict__ H2t_ws, const float* __restrict__ ybias_ws,
    const float* __restrict__ W2p,
    const float* __restrict__ Wm1, const float* __restrict__ bm1,
    const float* __restrict__ Wm2, const float* __restrict__ bm2,
    float* __restrict__ out) {
  __shared__ float s_H2t[36 * 132];                   // A: [j][k], k-padded
  __shared__ __align__(16) float s_pool[5120];        // X chunk [16][256] / partials [256][20]
  __shared__ int   s_seli[128];
  __shared__ float s_ybias[16];
  __shared__ float s_y[128];
  __shared__ float s_z[512];

  const int tid = threadIdx.x;
  const int q   = blockIdx.x >> 1;
  const int btg = blockIdx.x & 1;

  if (tid < 128) s_seli[tid] = seli_ws[q * 128 + tid];
  if (tid >= 128 && tid < 144) s_ybias[tid - 128] = ybias_ws[q * 16 + (tid - 128)];
  for (int idx = tid; idx < 4608; idx += 256) {
    const int j = idx >> 7, k = idx & 127;
    s_H2t[j * 132 + k] = H2t_ws[q * 4608 + idx];
  }
  __syncthreads();

  const int tj = tid >> 6, tp = tid & 63;
  float acc[9][4];
#pragma unroll
  for (int a = 0; a < 9; ++a)
#pragma unroll
    for (int b = 0; b < 4; ++b) acc[a][b] = 0.0f;

  float* s_X = s_pool;
  const size_t xbase = (size_t)btg * 8 * V_PTS * 32;

  for (int ch = 0; ch < 8; ++ch) {
    // stage 16k x 8bt x 32c chunk (raw x rows, coalesced 16B units)
#pragma unroll
    for (int uu = 0; uu < 4; ++uu) {
      const int unit = tid + uu * 256;
      const int k = unit >> 6, bt = (unit >> 3) & 7, six = unit & 7;
      const int v = s_seli[ch * 16 + k];
      const float4 val = *(const float4*)(x + xbase + ((size_t)bt * V_PTS + v) * 32 + six * 4);
      *(float4*)(s_X + k * 256 + bt * 32 + six * 4) = val;
    }
    __syncthreads();
#pragma unroll
    for (int kq = 0; kq < 4; ++kq) {
      float4 a4[9], b4[4];
#pragma unroll
      for (int jj = 0; jj < 9; ++jj)
        a4[jj] = *(const float4*)(s_H2t + (tj * 9 + jj) * 132 + ch * 16 + kq * 4);
#pragma unroll
      for (int kk = 0; kk < 4; ++kk)
        b4[kk] = *(const float4*)(s_X + (kq * 4 + kk) * 256 + tp * 4);
#pragma unroll
      for (int kk = 0; kk < 4; ++kk) {
#pragma unroll
        for (int jj = 0; jj < 9; ++jj) {
          const float ak = ((const float*)&a4[jj])[kk];
          const float* bp = (const float*)&b4[kk];
          acc[jj][0] = fmaf(ak, bp[0], acc[jj][0]);
          acc[jj][1] = fmaf(ak, bp[1], acc[jj][1]);
          acc[jj][2] = fmaf(ak, bp[2], acc[jj][2]);
          acc[jj][3] = fmaf(ak, bp[3], acc[jj][3]);
        }
      }
    }
    __syncthreads();
  }

  // epilogue: per-thread contraction of register G-tile with W2p (global, coalesced f4)
  float yac[16];
#pragma unroll
  for (int e = 0; e < 16; ++e) yac[e] = 0.0f;
#pragma unroll
  for (int jj = 0; jj < 9; ++jj) {
    const int j = tj * 9 + jj;
    if (j < 33) {
#pragma unroll
      for (int pp = 0; pp < 4; ++pp) {
        const int cp = (tp * 4 + pp) & 31;
        const float g = acc[jj][pp];
        const float4* w4 = (const float4*)(W2p + ((j * 32 + cp) << 4));
#pragma unroll
        for (int e = 0; e < 4; ++e) {
          const float4 w = w4[e];
          yac[e * 4 + 0] = fmaf(g, w.x, yac[e * 4 + 0]);
          yac[e * 4 + 1] = fmaf(g, w.y, yac[e * 4 + 1]);
          yac[e * 4 + 2] = fmaf(g, w.z, yac[e * 4 + 2]);
          yac[e * 4 + 3] = fmaf(g, w.w, yac[e * 4 + 3]);
        }
      }
    }
  }

  float* s_part = s_pool;   // reuse (s_X dead)
#pragma unroll
  for (int e = 0; e < 4; ++e)
    *(float4*)(s_part + tid * 20 + e * 4) =
        make_float4(yac[e * 4 + 0], yac[e * 4 + 1], yac[e * 4 + 2], yac[e * 4 + 3]);
  __syncthreads();

  if (tid < 128) {
    const int obt = tid >> 4, od = tid & 15;
    float y = s_ybias[od];
#pragma unroll
    for (int t2 = 0; t2 < 4; ++t2)
#pragma unroll
      for (int i = 0; i < 8; ++i) y += s_part[(t2 * 64 + obt * 8 + i) * 20 + od];
    s_y[obt * 16 + od] = gelu_erf(y);
  }
  __syncthreads();
  {
    const int obt = tid >> 5, hp = tid & 31;
#pragma unroll
    for (int e = 0; e < 2; ++e) {
      const int h = hp * 2 + e;
      float s = bm1[h];
#pragma unroll
      for (int d2 = 0; d2 < 16; ++d2) s = fmaf(s_y[obt * 16 + d2], Wm1[d2 * 64 + h], s);
      s_z[obt * 64 + h] = gelu_erf(s);
    }
  }
  __syncthreads();
  if (tid < 128) {
    const int obt = tid >> 4, od = tid & 15;
    float o = bm2[od];
#pragma unroll
    for (int h = 0; h < 64; ++h) o = fmaf(s_z[obt * 64 + h], Wm2[h * 16 + od], o);
    o += s_y[obt * 16 + od];
    out[((size_t)(btg * 8 + obt) * NQ + q) * 16 + od] = o;
  }
}

extern "C" void kernel_launch(void* const* d_in, const int* in_sizes, int n_in,
                              void* d_out, int out_size, void* d_ws, size_t ws_size,
                              hipStream_t stream) {
  const float* x    = (const float*)d_in[0];
  const float* pos  = (const float*)d_in[1];
  const float* qpos = (const float*)d_in[2];
  const float* qmw  = (const float*)d_in[3];
  const float* qmo  = (const float*)d_in[4];
  const float* Wl   = (const float*)d_in[5];
  const float* bl   = (const float*)d_in[6];
  const float* Brff = (const float*)d_in[7];
  const float* W1   = (const float*)d_in[8];
  const float* b1   = (const float*)d_in[9];
  const float* W2   = (const float*)d_in[10];
  const float* filt = (const float*)d_in[11];
  const float* bo   = (const float*)d_in[12];
  const float* Wm1  = (const float*)d_in[13];
  const float* bm1  = (const float*)d_in[14];
  const float* Wm2  = (const float*)d_in[15];
  const float* bm2  = (const float*)d_in[16];
  float* out = (float*)d_out;

  char* ws = (char*)d_ws;
  int*   seli_ws  = (int*)(ws + 0);                 // 1024*128*4   = 524,288
  float* H2t_ws   = (float*)(ws + 524288);          // 1024*4608*4  = 18,874,368
  float* ybias_ws = (float*)(ws + 19398656);        // 1024*16*4    = 65,536
  float* W2p_ws   = (float*)(ws + 19464192);        // 33*512*4     = 67,584
  float* W2b_ws   = (float*)(ws + 19531776);        // 33*16*4      = 2,112

  hipLaunchKernelGGL(prep_kernel, dim3(32), dim3(256), 0, stream,
                     Wl, bl, W2, filt, W2p_ws, W2b_ws);
  hipLaunchKernelGGL(sel_kernel, dim3(NQ), dim3(256), 0, stream,
                     pos, qpos, qmw, qmo, Brff, W1, b1, bo, W2b_ws,
                     seli_ws, H2t_ws, ybias_ws, out);
  hipLaunchKernelGGL(main_kernel, dim3(2048), dim3(256), 0, stream,
                     x, seli_ws, H2t_ws, ybias_ws, W2p_ws, Wm1, bm1, Wm2, bm2, out);
}